// Round 2
// baseline (13485.448 us; speedup 1.0000x reference)
//
#include <hip/hip_runtime.h>

typedef unsigned int u32;
typedef unsigned long long u64;

#define NPTS 2097152
#define NG 64
#define HP1 73856093LL
#define HP2 19349663LL
#define HP3 83492791LL
#define MASK40 ((1ULL<<40)-1)

#define CAP (1u<<22)          // hash table slots (>=2x worst-case uniques per pass)
#define CMASK (CAP-1u)
#define KEYMASK ((1ULL<<46)-1)
#define TAGSH 46
#define TAGMASK (0xFULL<<TAGSH)
#define BSHIFT 26             // rank-bucket = key>>26  -> 2^20 buckets
#define NBUCK (1u<<20)
#define BIGV 16               // voxels with count > BIGV go to the wave-fold path

struct Comp {
  u32 minE[3]; u32 maxE[3]; u32 nper; u32 cnt;
  float minx, miny, minz;
  float vlo, vhi, bestv;
  int s_c; int bestdiff;
};

// ---- helpers ----------------------------------------------------------------
__device__ __forceinline__ u32 encf(float f) {
  u32 u = __float_as_uint(f);
  return (u & 0x80000000u) ? ~u : (u | 0x80000000u);
}
__device__ __forceinline__ float decf(u32 u) {
  return (u & 0x80000000u) ? __uint_as_float(u & 0x7FFFFFFFu) : __uint_as_float(~u);
}
__device__ __forceinline__ u32 hash_key(u64 k) {
  k ^= k >> 33; k *= 0xff51afd7ed558ccdULL;
  k ^= k >> 33; k *= 0xc4ceb9fe1a85ec53ULL;
  k ^= k >> 33;
  return (u32)k & CMASK;
}
__device__ __forceinline__ u64 make_key(float x, float y, float z, int c,
                                        float mnx, float mny, float mnz, float v) {
  // exact replication of: floor((xyz - mins[comp]) / v)  (f32 IEEE sub + div + floor)
  float fx = floorf((x - mnx) / v);
  float fy = floorf((y - mny) / v);
  float fz = floorf((z - mnz) / v);
  long long ix = (long long)fx, iy = (long long)fy, iz = (long long)fz;
  u64 h = (u64)((ix * HP1) ^ (iy * HP2) ^ (iz * HP3));
  return ((u64)c << 40) | (h & MASK40);
}
// tagged insert driven ONLY by atomicCAS return values (no plain loads of tab):
// a plain load can be stale/torn vs concurrent L2 atomics -> duplicate inserts
// (the round-1 nondeterminism). Returns true iff this thread inserted the key.
__device__ __forceinline__ bool tab_insert(u64* tab, u64 key, u64 tag) {
  u64 want = tag | key;
  u32 s = hash_key(key);
  u64 cur = 0;  // optimistic: empty slot
  for (;;) {
    u64 old = atomicCAS(tab + s, cur, want);
    if (old == cur) return true;    // we claimed the slot
    if (old == want) return false;  // same key already inserted this pass
    if ((old & TAGMASK) == tag) { s = (s + 1) & CMASK; cur = 0; continue; }  // other live key
    cur = old;                      // stale entry: retry same slot with true expected
  }
}

// ---- per-comp setup ---------------------------------------------------------
__global__ void k_init_comp(Comp* cc, u32* uniqueM, u32* bigCnt) {
  int c = threadIdx.x;
  if (c < NG) {
    for (int k = 0; k < 3; ++k) { cc[c].minE[k] = 0xFFFFFFFFu; cc[c].maxE[k] = 0u; }
    cc[c].nper = 0u; cc[c].cnt = 0u;
  }
  if (c == 0) { *uniqueM = 0u; *bigCnt = 0u; }
}

__global__ void k_bbox(const float* __restrict__ xyz, const int* __restrict__ comp,
                       Comp* cc, int n) {
  __shared__ u32 smin[NG * 3], smax[NG * 3], scnt[NG];
  int t = threadIdx.x;
  for (int k = t; k < NG * 3; k += blockDim.x) { smin[k] = 0xFFFFFFFFu; smax[k] = 0u; }
  for (int k = t; k < NG; k += blockDim.x) scnt[k] = 0u;
  __syncthreads();
  for (int i = blockIdx.x * blockDim.x + t; i < n; i += gridDim.x * blockDim.x) {
    int c = comp[i];
    float x = xyz[3 * i], y = xyz[3 * i + 1], z = xyz[3 * i + 2];
    atomicMin(&smin[c * 3 + 0], encf(x)); atomicMax(&smax[c * 3 + 0], encf(x));
    atomicMin(&smin[c * 3 + 1], encf(y)); atomicMax(&smax[c * 3 + 1], encf(y));
    atomicMin(&smin[c * 3 + 2], encf(z)); atomicMax(&smax[c * 3 + 2], encf(z));
    atomicAdd(&scnt[c], 1u);
  }
  __syncthreads();
  for (int c = t; c < NG; c += blockDim.x) {
    if (scnt[c]) {
      atomicMin(&cc[c].minE[0], smin[c * 3 + 0]); atomicMax(&cc[c].maxE[0], smax[c * 3 + 0]);
      atomicMin(&cc[c].minE[1], smin[c * 3 + 1]); atomicMax(&cc[c].maxE[1], smax[c * 3 + 1]);
      atomicMin(&cc[c].minE[2], smin[c * 3 + 2]); atomicMax(&cc[c].maxE[2], smax[c * 3 + 2]);
      atomicAdd(&cc[c].nper, scnt[c]);
    }
  }
}

__global__ void k_setup(Comp* cc, const int* __restrict__ salloc) {
  int c = threadIdx.x;
  if (c >= NG) return;
  Comp& C = cc[c];
  float mnx = decf(C.minE[0]), mny = decf(C.minE[1]), mnz = decf(C.minE[2]);
  float mxx = decf(C.maxE[0]), mxy = decf(C.maxE[1]), mxz = decf(C.maxE[2]);
  float spx = fmaxf(mxx - mnx, 1e-6f), spy = fmaxf(mxy - mny, 1e-6f), spz = fmaxf(mxz - mnz, 1e-6f);
  float ssx = fmaxf(spx, 0.05f), ssy = fmaxf(spy, 0.05f), ssz = fmaxf(spz, 0.05f);
  float vol = (ssx * ssy) * ssz;                  // left-assoc like XLA
  long long npr = (long long)C.nper;
  long long hi = npr > 1 ? npr : 1;
  long long sc = (long long)salloc[c];
  if (sc < 1) sc = 1;
  if (sc > hi) sc = hi;
  float scf = fmaxf((float)sc, 1.0f);
  float base = vol / scf;
  // f64 pow rounded to f32 == correctly-rounded f32 pow (matches glibc powf)
  float v0 = (float)pow((double)base, (double)(1.0f / 3.0f));
  C.minx = mnx; C.miny = mny; C.minz = mnz;
  C.vlo = fmaxf(v0 * 0.1f, 1e-4f);
  C.vhi = fmaxf(v0 * 64.0f, 1e-4f);
  C.bestv = v0; C.bestdiff = 1 << 30;
  C.s_c = (int)sc; C.cnt = 0u;
}

__global__ void k_bisect_insert(const float* __restrict__ xyz, const int* __restrict__ comp,
                                Comp* cc, u64* tab, u64 tag) {
  __shared__ u32 scnt[NG];
  int t = threadIdx.x;
  if (t < NG) scnt[t] = 0u;
  __syncthreads();
  int i = blockIdx.x * 256 + t;
  int c = comp[i];
  float vmid = (cc[c].vlo + cc[c].vhi) * 0.5f;     // same f32 result in all lanes
  u64 key = make_key(xyz[3 * i], xyz[3 * i + 1], xyz[3 * i + 2], c,
                     cc[c].minx, cc[c].miny, cc[c].minz, vmid);
  if (tab_insert(tab, key, tag)) atomicAdd(&scnt[c], 1u);
  __syncthreads();
  if (t < NG && scnt[t]) atomicAdd(&cc[t].cnt, scnt[t]);
}

__global__ void k_update(Comp* cc) {
  int c = threadIdx.x;
  if (c >= NG) return;
  Comp& C = cc[c];
  float vmid = (C.vlo + C.vhi) * 0.5f;
  int cnt = (int)C.cnt;
  int d = cnt - C.s_c; if (d < 0) d = -d;
  if (d < C.bestdiff) { C.bestdiff = d; C.bestv = vmid; }
  if (cnt > C.s_c) C.vlo = vmid; else C.vhi = vmid;
  C.cnt = 0u;
}

__global__ void k_final_insert(const float* __restrict__ xyz, const int* __restrict__ comp,
                               Comp* cc, u64* tab, u32* uniqueM) {
  __shared__ u32 sM;
  int t = threadIdx.x;
  if (t == 0) sM = 0u;
  __syncthreads();
  int i = blockIdx.x * 256 + t;
  int c = comp[i];
  u64 key = make_key(xyz[3 * i], xyz[3 * i + 1], xyz[3 * i + 2], c,
                     cc[c].minx, cc[c].miny, cc[c].minz, cc[c].bestv);
  if (tab_insert(tab, key, 9ULL << TAGSH)) atomicAdd(&sM, 1u);
  __syncthreads();
  if (t == 0 && sM) atomicAdd(uniqueM, sM);
}

// ---- unique-rank (== jnp.unique inverse) ------------------------------------
__global__ void k_hist_table(const u64* __restrict__ tab, u32* bcnt) {
  u32 i = blockIdx.x * 256 + threadIdx.x;
  u64 e = tab[i];
  if ((e & TAGMASK) == (9ULL << TAGSH))
    atomicAdd(&bcnt[(u32)((e & KEYMASK) >> BSHIFT)], 1u);
}
__global__ void k_scatter_table(const u64* __restrict__ tab, const u32* __restrict__ boff,
                                u32* bfill, u64* bkeys) {
  u32 i = blockIdx.x * 256 + threadIdx.x;
  u64 e = tab[i];
  if ((e & TAGMASK) == (9ULL << TAGSH)) {
    u64 key = e & KEYMASK;
    u32 b = (u32)(key >> BSHIFT);
    u32 pos = boff[b] + atomicAdd(&bfill[b], 1u);
    bkeys[pos] = key;
  }
}
__global__ void k_rank(const u64* __restrict__ bkeys, const u32* __restrict__ bcnt,
                       const u32* __restrict__ boff, const u64* __restrict__ tab,
                       u32* rankArr, const u32* __restrict__ uniqueM) {
  u32 p = blockIdx.x * 256 + threadIdx.x;
  if (p >= *uniqueM) return;
  u64 key = bkeys[p];
  u32 b = (u32)(key >> BSHIFT);
  u32 st = boff[b], cn = bcnt[b];
  u32 r = st;
  for (u32 q = st; q < st + cn; ++q) r += (bkeys[q] < key) ? 1u : 0u;
  u64 want = (9ULL << TAGSH) | key;
  u32 s = hash_key(key);
  while (tab[s] != want) s = (s + 1) & CMASK;   // quiescent table: plain reads safe
  rankArr[s] = r;
}
__global__ void k_inv(const float* __restrict__ xyz, const int* __restrict__ comp,
                      const Comp* __restrict__ cc, const u64* __restrict__ tab,
                      const u32* __restrict__ rankArr, u32* inv, u32* counts) {
  int i = blockIdx.x * 256 + threadIdx.x;
  int c = comp[i];
  u64 key = make_key(xyz[3 * i], xyz[3 * i + 1], xyz[3 * i + 2], c,
                     cc[c].minx, cc[c].miny, cc[c].minz, cc[c].bestv);
  u64 want = (9ULL << TAGSH) | key;
  u32 s = hash_key(key);
  while (tab[s] != want) s = (s + 1) & CMASK;
  u32 r = rankArr[s];
  inv[i] = r;
  atomicAdd(&counts[r], 1u);
}

__global__ void k_pairs(const u32* __restrict__ inv, u64* pairA) {
  int i = blockIdx.x * 256 + threadIdx.x;
  pairA[i] = ((u64)inv[i] << 32) | (u32)i;
}

// ---- generic exclusive scan (3 kernels) -------------------------------------
__global__ void k_scan_part(const u32* __restrict__ in, u32* part, int n) {
  __shared__ u32 sh[256];
  int t = threadIdx.x;
  int base = blockIdx.x * 2048 + t * 8;
  u32 s = 0;
  for (int k = 0; k < 8; ++k) { int i = base + k; if (i < n) s += in[i]; }
  sh[t] = s; __syncthreads();
  for (int off = 1; off < 256; off <<= 1) {
    u32 a = (t >= off) ? sh[t - off] : 0u; __syncthreads();
    sh[t] += a; __syncthreads();
  }
  if (t == 255) part[blockIdx.x] = sh[255];
}
__global__ __launch_bounds__(1024) void k_scan_single(u32* a, int n) {
  __shared__ u32 sh[1024];
  int t = threadIdx.x;
  u32 v = (t < n) ? a[t] : 0u;
  sh[t] = v; __syncthreads();
  for (int off = 1; off < 1024; off <<= 1) {
    u32 x = (t >= off) ? sh[t - off] : 0u; __syncthreads();
    sh[t] += x; __syncthreads();
  }
  if (t < n) a[t] = sh[t] - v;
}
__global__ void k_scan_apply(const u32* __restrict__ in, const u32* __restrict__ part,
                             u32* out, int n) {
  __shared__ u32 sh[256];
  int t = threadIdx.x;
  int base = blockIdx.x * 2048 + t * 8;
  u32 vals[8]; u32 s = 0;
  for (int k = 0; k < 8; ++k) { int i = base + k; vals[k] = (i < n) ? in[i] : 0u; s += vals[k]; }
  sh[t] = s; __syncthreads();
  for (int off = 1; off < 256; off <<= 1) {
    u32 x = (t >= off) ? sh[t - off] : 0u; __syncthreads();
    sh[t] += x; __syncthreads();
  }
  u32 tb = sh[t] - s + part[blockIdx.x];
  u32 run = 0;
  for (int k = 0; k < 8; ++k) { int i = base + k; if (i < n) out[i] = tb + run; run += vals[k]; }
}

// ---- stable 7-bit LSD radix pass (sort pairs by inv; stability => idx order) -
__global__ __launch_bounds__(64) void k_radix_hist(const u64* __restrict__ src, u32* gh, int shift) {
  __shared__ u32 h[128 * 64];
  int t = threadIdx.x;
  for (int k = t; k < 128 * 64; k += 64) h[k] = 0u;
  __syncthreads();
  int base = blockIdx.x * 2048 + t * 32;
  for (int k = 0; k < 32; ++k) { u32 d = (u32)(src[base + k] >> shift) & 127u; h[d * 64 + t]++; }
  __syncthreads();
  for (int d = t; d < 128; d += 64) {
    u32 s = 0;
    for (int tt = 0; tt < 64; ++tt) s += h[d * 64 + tt];
    gh[d * 1024 + blockIdx.x] = s;
  }
}
__global__ __launch_bounds__(64) void k_radix_scatter(const u64* __restrict__ src, u64* dst,
                                                      const u32* __restrict__ ghs, int shift) {
  __shared__ u32 h[128 * 64]; __shared__ u32 sb[128];
  int t = threadIdx.x;
  for (int k = t; k < 128 * 64; k += 64) h[k] = 0u;
  __syncthreads();
  int base = blockIdx.x * 2048 + t * 32;
  for (int k = 0; k < 32; ++k) { u32 d = (u32)(src[base + k] >> shift) & 127u; h[d * 64 + t]++; }
  __syncthreads();
  for (int d = t; d < 128; d += 64) {
    u32 run = 0;
    for (int tt = 0; tt < 64; ++tt) { u32 tmp = h[d * 64 + tt]; h[d * 64 + tt] = run; run += tmp; }
    sb[d] = ghs[d * 1024 + blockIdx.x];
  }
  __syncthreads();
  for (int k = 0; k < 32; ++k) {
    u64 v = src[base + k];
    u32 d = (u32)(v >> shift) & 127u;
    u32 pos = sb[d] + h[d * 64 + t];
    h[d * 64 + t]++;
    dst[pos] = v;
  }
}

// ---- in-index-order f32 sums per voxel (bit-exact vs sequential scatter-add) -
__global__ void k_sum_small(const u32* __restrict__ counts, const u32* __restrict__ voxOff,
                            const u64* __restrict__ pairF, const float* __restrict__ xyz,
                            float* centx, float* centy, float* centz,
                            u32* bigList, u32* bigCnt) {
  int v = blockIdx.x * 256 + threadIdx.x;
  u32 c = counts[v];
  if (!c) return;
  if (c > BIGV) { bigList[atomicAdd(bigCnt, 1u)] = (u32)v; return; }
  u32 off = voxOff[v];
  float sx = 0.f, sy = 0.f, sz = 0.f;
  for (u32 q = 0; q < c; ++q) {
    u32 idx = (u32)(pairF[off + q] & 0xFFFFFFFFULL);
    sx += xyz[3 * idx];
    sy += xyz[3 * idx + 1];
    sz += xyz[3 * idx + 2];
  }
  float fc = (float)c;
  centx[v] = sx / fc; centy[v] = sy / fc; centz[v] = sz / fc;
}
// one wave per big voxel: cooperative gather into LDS (double-buffered), then
// an in-order serial fold from LDS (all lanes redundantly -> broadcast, free).
// Order of adds is ascending point index (pairs are stably sorted) == reference.
__global__ __launch_bounds__(64) void k_sum_big(const u32* __restrict__ bigCnt,
                                                const u32* __restrict__ bigList,
                                                const u32* __restrict__ counts,
                                                const u32* __restrict__ voxOff,
                                                const u64* __restrict__ pairF,
                                                const float* __restrict__ xyz,
                                                float* centx, float* centy, float* centz) {
  __shared__ float bx[2][64], by[2][64], bz[2][64];
  int t = threadIdx.x;
  u32 nb = *bigCnt;
  for (u32 b = blockIdx.x; b < nb; b += gridDim.x) {
    u32 v = bigList[b];
    u32 c = counts[v];
    u32 off = voxOff[v];
    u32 nchunk = (c + 63u) >> 6;
    if ((u32)t < c) {
      u32 idx = (u32)(pairF[off + t] & 0xFFFFFFFFULL);
      bx[0][t] = xyz[3 * idx]; by[0][t] = xyz[3 * idx + 1]; bz[0][t] = xyz[3 * idx + 2];
    }
    __syncthreads();
    float sx = 0.f, sy = 0.f, sz = 0.f;
    int cur = 0;
    for (u32 ch = 0; ch < nchunk; ++ch) {
      u32 basen = (ch + 1) << 6;
      if (ch + 1 < nchunk && basen + (u32)t < c) {
        u32 idx = (u32)(pairF[off + basen + t] & 0xFFFFFFFFULL);
        bx[cur ^ 1][t] = xyz[3 * idx]; by[cur ^ 1][t] = xyz[3 * idx + 1]; bz[cur ^ 1][t] = xyz[3 * idx + 2];
      }
      u32 base = ch << 6;
      u32 m = c - base; if (m > 64u) m = 64u;
      for (u32 q = 0; q < m; ++q) { sx += bx[cur][q]; sy += by[cur][q]; sz += bz[cur][q]; }
      __syncthreads();
      cur ^= 1;
    }
    if (t == 0) {
      float fc = (float)c;
      centx[v] = sx / fc; centy[v] = sy / fc; centz[v] = sz / fc;
    }
    __syncthreads();
  }
}

__global__ void k_d(const float* __restrict__ xyz, const u32* __restrict__ inv,
                    const float* __restrict__ centx, const float* __restrict__ centy,
                    const float* __restrict__ centz, float* dArr, u32* dminb) {
  int i = blockIdx.x * 256 + threadIdx.x;
  u32 v = inv[i];
  float dx = xyz[3 * i] - centx[v];
  float dy = xyz[3 * i + 1] - centy[v];
  float dz = xyz[3 * i + 2] - centz[v];
  // no-FMA sum of squares, left-assoc (matches XLA reduce order)
  float dd = __fadd_rn(__fadd_rn(__fmul_rn(dx, dx), __fmul_rn(dy, dy)), __fmul_rn(dz, dz));
  dArr[i] = dd;
  atomicMin(&dminb[v], __float_as_uint(dd));  // dd >= 0: uint order == float order
}
__global__ void k_amin(const float* __restrict__ dArr, const u32* __restrict__ inv,
                       const u32* __restrict__ dminb, u32* amin) {
  int i = blockIdx.x * 256 + threadIdx.x;
  u32 v = inv[i];
  if (dArr[i] <= __uint_as_float(dminb[v])) atomicMin(&amin[v], (u32)i);
}
__global__ void k_out(const u32* __restrict__ counts, const u32* __restrict__ amin,
                      const float* __restrict__ xyz, float* out) {
  int j = blockIdx.x * 256 + threadIdx.x;
  u32 c = counts[j];
  float ox = 0.f, oy = 0.f, oz = 0.f, og = -1.0f, ov = 0.0f;
  if (c) {
    u32 idx = amin[j];
    ox = xyz[3 * idx]; oy = xyz[3 * idx + 1]; oz = xyz[3 * idx + 2];
    og = (float)idx; ov = 1.0f;
  }
  out[3 * j] = ox; out[3 * j + 1] = oy; out[3 * j + 2] = oz;
  out[3 * NPTS + j] = og;
  out[4 * NPTS + j] = ov;
}

// ---- launch -----------------------------------------------------------------
extern "C" void kernel_launch(void* const* d_in, const int* in_sizes, int n_in,
                              void* d_out, int out_size, void* d_ws, size_t ws_size,
                              hipStream_t stream) {
  const float* xyz = (const float*)d_in[0];
  const int* comp = (const int*)d_in[1];
  const int* salloc = (const int*)d_in[2];
  float* out = (float*)d_out;
  char* ws = (char*)d_ws;

  const size_t SZN = (size_t)NPTS * 4;
  size_t oGH = 8192;                     // 512KB
  size_t oPART = oGH + 524288;           // 4KB
  size_t oINV = 1u << 20;
  size_t oCNT = oINV + SZN;
  size_t oVOX = oCNT + SZN;
  size_t oD = oVOX + SZN;
  size_t oDMIN = oD + SZN;
  size_t oAMIN = oDMIN + SZN;
  size_t oCENT = oAMIN + SZN;            // 3*SZN
  size_t oPA = oCENT + 3 * SZN;
  size_t oPB = oPA + (size_t)NPTS * 8;
  size_t NEED = oPB + (size_t)NPTS * 8;  // ~105MB (tab spans pairA+pairB)
  if (ws_size < NEED) return;

  Comp* cc = (Comp*)(ws);
  u32* uniqueM = (u32*)(ws + 6144);
  u32* bigCnt = (u32*)(ws + 6208);
  u32* gh = (u32*)(ws + oGH);
  u32* part = (u32*)(ws + oPART);
  u32* inv = (u32*)(ws + oINV);
  u32* counts = (u32*)(ws + oCNT);
  u32* voxOff = (u32*)(ws + oVOX);
  float* dArr = (float*)(ws + oD);
  u32* dminb = (u32*)(ws + oDMIN);
  u32* amin = (u32*)(ws + oAMIN);
  float* centx = (float*)(ws + oCENT);
  float* centy = (float*)(ws + oCENT + SZN);
  float* centz = (float*)(ws + oCENT + 2 * SZN);
  u64* pairA = (u64*)(ws + oPA);
  u64* pairB = (u64*)(ws + oPB);
  // unions (liveness-disjoint):
  u64* tab = (u64*)(ws + oPA);           // 32MB over pairA+pairB; dead before k_pairs
  u32* rankArr = (u32*)(ws + oCENT);     // 16MB over cent; dead before k_sum_*
  u64* bkeys = (u64*)(ws + oCNT);        // 16MB over counts+voxOff; dead before memset(counts)
  u32* bcnt = (u32*)(ws + oD);           // 4MB over dArr; dead after k_rank
  u32* boff = (u32*)(ws + oD + 4194304); // 4MB over dArr
  u32* bfill = (u32*)(ws + oDMIN);       // 4MB over dminb; dead before memset(dminb)
  u32* bigList = (u32*)(ws + oD);        // over dArr; live k_sum_small..k_sum_big < k_d
                                         // NOTE: bigList overlaps bcnt/boff (dead after k_rank)

  // Phase A: bbox + per-comp setup
  k_init_comp<<<1, 64, 0, stream>>>(cc, uniqueM, bigCnt);
  k_bbox<<<1024, 256, 0, stream>>>(xyz, comp, cc, NPTS);
  k_setup<<<1, 64, 0, stream>>>(cc, salloc);
  hipMemsetAsync(tab, 0, (size_t)CAP * 8, stream);

  // Phase B: 8-iteration bisection on distinct-voxel count (tagged hash set)
  for (int it = 0; it < 8; ++it) {
    k_bisect_insert<<<NPTS / 256, 256, 0, stream>>>(xyz, comp, cc, tab, ((u64)(it + 1)) << TAGSH);
    k_update<<<1, 64, 0, stream>>>(cc);
  }

  // Phase C: final voxelization + sorted-unique ranks
  k_final_insert<<<NPTS / 256, 256, 0, stream>>>(xyz, comp, cc, tab, uniqueM);
  hipMemsetAsync(bcnt, 0, (size_t)NBUCK * 4, stream);
  hipMemsetAsync(bfill, 0, (size_t)NBUCK * 4, stream);
  k_hist_table<<<CAP / 256, 256, 0, stream>>>(tab, bcnt);
  k_scan_part<<<512, 256, 0, stream>>>(bcnt, part, NBUCK);
  k_scan_single<<<1, 1024, 0, stream>>>(part, 512);
  k_scan_apply<<<512, 256, 0, stream>>>(bcnt, part, boff, NBUCK);
  k_scatter_table<<<CAP / 256, 256, 0, stream>>>(tab, boff, bfill, bkeys);
  k_rank<<<NPTS / 256, 256, 0, stream>>>(bkeys, bcnt, boff, tab, rankArr, uniqueM);

  // Phase D: inv + counts, offsets, stable sort by inv
  hipMemsetAsync(counts, 0, SZN, stream);          // kills bkeys (dead)
  k_inv<<<NPTS / 256, 256, 0, stream>>>(xyz, comp, cc, tab, rankArr, inv, counts);
  k_scan_part<<<1024, 256, 0, stream>>>(counts, part, NPTS);
  k_scan_single<<<1, 1024, 0, stream>>>(part, 1024);
  k_scan_apply<<<1024, 256, 0, stream>>>(counts, part, voxOff, NPTS);
  k_pairs<<<NPTS / 256, 256, 0, stream>>>(inv, pairA);  // kills tab (dead)
  {
    const int shifts[3] = {32, 39, 46};  // inv occupies bits 32..52
    u64* src = pairA; u64* dst = pairB;
    for (int p = 0; p < 3; ++p) {
      k_radix_hist<<<1024, 64, 0, stream>>>(src, gh, shifts[p]);
      k_scan_part<<<64, 256, 0, stream>>>(gh, part, 131072);
      k_scan_single<<<1, 1024, 0, stream>>>(part, 64);
      k_scan_apply<<<64, 256, 0, stream>>>(gh, part, gh, 131072);
      k_radix_scatter<<<1024, 64, 0, stream>>>(src, dst, gh, shifts[p]);
      u64* t2 = src; src = dst; dst = t2;
    }
    // sorted pairs now in pairB (src)
    k_sum_small<<<NPTS / 256, 256, 0, stream>>>(counts, voxOff, src, xyz,
                                                centx, centy, centz, bigList, bigCnt);
    k_sum_big<<<4096, 64, 0, stream>>>(bigCnt, bigList, counts, voxOff, src, xyz,
                                       centx, centy, centz);
  }

  // Phase E: distances, argmin, outputs
  hipMemsetAsync(dminb, 0xFF, SZN, stream);        // kills bfill (dead)
  hipMemsetAsync(amin, 0xFF, SZN, stream);
  k_d<<<NPTS / 256, 256, 0, stream>>>(xyz, inv, centx, centy, centz, dArr, dminb);
  k_amin<<<NPTS / 256, 256, 0, stream>>>(dArr, inv, dminb, amin);
  k_out<<<NPTS / 256, 256, 0, stream>>>(counts, amin, xyz, out);
}

// Round 3
// 3270.346 us; speedup vs baseline: 4.1236x; 4.1236x over previous
//
#include <hip/hip_runtime.h>

typedef unsigned int u32;
typedef unsigned long long u64;

#define NPTS 2097152
#define NG 64
#define HP1 73856093LL
#define HP2 19349663LL
#define HP3 83492791LL
#define MASK40 ((1ULL<<40)-1)

#define CAP (1u<<22)          // hash table slots (>=2x worst-case uniques per pass)
#define CMASK (CAP-1u)
#define KEYMASK ((1ULL<<46)-1)
#define BIT62 (1ULL<<62)      // presence bit so ekey != 0 even for key 0
#define BSHIFT 26             // rank-bucket = key>>26  -> 2^20 buckets
#define NBUCK (1u<<20)
#define BIGV 16               // voxels with count > BIGV go to the wave-fold path
#define LT 512                // per-block LDS dedup table slots

struct Comp {
  u32 minE[3]; u32 maxE[3]; u32 nper; u32 cnt;
  float minx, miny, minz;
  float vlo, vhi, bestv;
  int s_c; int bestdiff;
};

// ---- helpers ----------------------------------------------------------------
__device__ __forceinline__ u32 encf(float f) {
  u32 u = __float_as_uint(f);
  return (u & 0x80000000u) ? ~u : (u | 0x80000000u);
}
__device__ __forceinline__ float decf(u32 u) {
  return (u & 0x80000000u) ? __uint_as_float(u & 0x7FFFFFFFu) : __uint_as_float(~u);
}
__device__ __forceinline__ u32 hash_key(u64 k) {
  k ^= k >> 33; k *= 0xff51afd7ed558ccdULL;
  k ^= k >> 33; k *= 0xc4ceb9fe1a85ec53ULL;
  k ^= k >> 33;
  return (u32)k & CMASK;
}
__device__ __forceinline__ u64 make_key(float x, float y, float z, int c,
                                        float mnx, float mny, float mnz, float v) {
  // exact replication of: floor((xyz - mins[comp]) / v)  (f32 IEEE sub + div + floor)
  float fx = floorf((x - mnx) / v);
  float fy = floorf((y - mny) / v);
  float fz = floorf((z - mnz) / v);
  long long ix = (long long)fx, iy = (long long)fy, iz = (long long)fz;
  u64 h = (u64)((ix * HP1) ^ (iy * HP2) ^ (iz * HP3));
  return ((u64)c << 40) | (h & MASK40);
}

// Global insert into a table that was ZEROED before this pass.
// Slots only transition 0 -> some ekey, never back. The relaxed pre-load can
// only cause a skip when it reads exactly our ekey (which is then truly
// present); every inserting decision is driven by the atomicCAS return value,
// so duplicates are impossible.
__device__ __forceinline__ bool tab_insert0(u64* tab, u64 ekey) {
  u32 s = hash_key(ekey);
  for (;;) {
    u64 cur = __hip_atomic_load(&tab[s], __ATOMIC_RELAXED, __HIP_MEMORY_SCOPE_AGENT);
    if (cur == ekey) return false;          // already present (hot-line fast path)
    if (cur == 0) {
      u64 old = atomicCAS(tab + s, 0ULL, ekey);
      if (old == 0) return true;            // we claimed it
      if (old == ekey) return false;        // racer inserted same key
      // old = other key -> continue probing
    }
    s = (s + 1) & CMASK;
  }
}

// Per-block LDS dedup: returns true iff this thread is the block-local owner
// of ekey (only the owner attempts the global insert).
__device__ __forceinline__ bool lds_claim(u64* lt, u64 ekey) {
  u32 s = (u32)((ekey * 0x9E3779B97F4A7C15ULL) >> 49) & (LT - 1u);
  for (;;) {
    u64 old = atomicCAS(&lt[s], 0ULL, ekey);
    if (old == 0) return true;
    if (old == ekey) return false;
    s = (s + 1) & (LT - 1u);
  }
}

// ---- per-comp setup ---------------------------------------------------------
__global__ void k_init_comp(Comp* cc, u32* uniqueM, u32* bigCnt) {
  int c = threadIdx.x;
  if (c < NG) {
    for (int k = 0; k < 3; ++k) { cc[c].minE[k] = 0xFFFFFFFFu; cc[c].maxE[k] = 0u; }
    cc[c].nper = 0u; cc[c].cnt = 0u;
  }
  if (c == 0) { *uniqueM = 0u; *bigCnt = 0u; }
}

__global__ void k_bbox(const float* __restrict__ xyz, const int* __restrict__ comp,
                       Comp* cc, int n) {
  __shared__ u32 smin[NG * 3], smax[NG * 3], scnt[NG];
  int t = threadIdx.x;
  for (int k = t; k < NG * 3; k += blockDim.x) { smin[k] = 0xFFFFFFFFu; smax[k] = 0u; }
  for (int k = t; k < NG; k += blockDim.x) scnt[k] = 0u;
  __syncthreads();
  for (int i = blockIdx.x * blockDim.x + t; i < n; i += gridDim.x * blockDim.x) {
    int c = comp[i];
    float x = xyz[3 * i], y = xyz[3 * i + 1], z = xyz[3 * i + 2];
    atomicMin(&smin[c * 3 + 0], encf(x)); atomicMax(&smax[c * 3 + 0], encf(x));
    atomicMin(&smin[c * 3 + 1], encf(y)); atomicMax(&smax[c * 3 + 1], encf(y));
    atomicMin(&smin[c * 3 + 2], encf(z)); atomicMax(&smax[c * 3 + 2], encf(z));
    atomicAdd(&scnt[c], 1u);
  }
  __syncthreads();
  for (int c = t; c < NG; c += blockDim.x) {
    if (scnt[c]) {
      atomicMin(&cc[c].minE[0], smin[c * 3 + 0]); atomicMax(&cc[c].maxE[0], smax[c * 3 + 0]);
      atomicMin(&cc[c].minE[1], smin[c * 3 + 1]); atomicMax(&cc[c].maxE[1], smax[c * 3 + 1]);
      atomicMin(&cc[c].minE[2], smin[c * 3 + 2]); atomicMax(&cc[c].maxE[2], smax[c * 3 + 2]);
      atomicAdd(&cc[c].nper, scnt[c]);
    }
  }
}

__global__ void k_setup(Comp* cc, const int* __restrict__ salloc) {
  int c = threadIdx.x;
  if (c >= NG) return;
  Comp& C = cc[c];
  float mnx = decf(C.minE[0]), mny = decf(C.minE[1]), mnz = decf(C.minE[2]);
  float mxx = decf(C.maxE[0]), mxy = decf(C.maxE[1]), mxz = decf(C.maxE[2]);
  float spx = fmaxf(mxx - mnx, 1e-6f), spy = fmaxf(mxy - mny, 1e-6f), spz = fmaxf(mxz - mnz, 1e-6f);
  float ssx = fmaxf(spx, 0.05f), ssy = fmaxf(spy, 0.05f), ssz = fmaxf(spz, 0.05f);
  float vol = (ssx * ssy) * ssz;                  // left-assoc like XLA
  long long npr = (long long)C.nper;
  long long hi = npr > 1 ? npr : 1;
  long long sc = (long long)salloc[c];
  if (sc < 1) sc = 1;
  if (sc > hi) sc = hi;
  float scf = fmaxf((float)sc, 1.0f);
  float base = vol / scf;
  // f64 pow rounded to f32 == correctly-rounded f32 pow (matches glibc powf)
  float v0 = (float)pow((double)base, (double)(1.0f / 3.0f));
  C.minx = mnx; C.miny = mny; C.minz = mnz;
  C.vlo = fmaxf(v0 * 0.1f, 1e-4f);
  C.vhi = fmaxf(v0 * 64.0f, 1e-4f);
  C.bestv = v0; C.bestdiff = 1 << 30;
  C.s_c = (int)sc; C.cnt = 0u;
}

__global__ void k_bisect_insert(const float* __restrict__ xyz, const int* __restrict__ comp,
                                Comp* cc, u64* tab) {
  __shared__ u64 lt[LT];
  __shared__ u32 scnt[NG];
  int t = threadIdx.x;
  lt[t] = 0; lt[t + 256] = 0;
  if (t < NG) scnt[t] = 0u;
  __syncthreads();
  int i = blockIdx.x * 256 + t;
  int c = comp[i];
  float vmid = (cc[c].vlo + cc[c].vhi) * 0.5f;     // same f32 result in all lanes
  u64 key = make_key(xyz[3 * i], xyz[3 * i + 1], xyz[3 * i + 2], c,
                     cc[c].minx, cc[c].miny, cc[c].minz, vmid);
  u64 ekey = key | BIT62;
  if (lds_claim(lt, ekey) && tab_insert0(tab, ekey)) atomicAdd(&scnt[c], 1u);
  __syncthreads();
  if (t < NG && scnt[t]) atomicAdd(&cc[t].cnt, scnt[t]);
}

__global__ void k_update(Comp* cc) {
  int c = threadIdx.x;
  if (c >= NG) return;
  Comp& C = cc[c];
  float vmid = (C.vlo + C.vhi) * 0.5f;
  int cnt = (int)C.cnt;
  int d = cnt - C.s_c; if (d < 0) d = -d;
  if (d < C.bestdiff) { C.bestdiff = d; C.bestv = vmid; }
  if (cnt > C.s_c) C.vlo = vmid; else C.vhi = vmid;
  C.cnt = 0u;
}

__global__ void k_final_insert(const float* __restrict__ xyz, const int* __restrict__ comp,
                               Comp* cc, u64* tab, u32* uniqueM) {
  __shared__ u64 lt[LT];
  __shared__ u32 sM;
  int t = threadIdx.x;
  lt[t] = 0; lt[t + 256] = 0;
  if (t == 0) sM = 0u;
  __syncthreads();
  int i = blockIdx.x * 256 + t;
  int c = comp[i];
  u64 key = make_key(xyz[3 * i], xyz[3 * i + 1], xyz[3 * i + 2], c,
                     cc[c].minx, cc[c].miny, cc[c].minz, cc[c].bestv);
  u64 ekey = key | BIT62;
  if (lds_claim(lt, ekey) && tab_insert0(tab, ekey)) atomicAdd(&sM, 1u);
  __syncthreads();
  if (t == 0 && sM) atomicAdd(uniqueM, sM);
}

// ---- unique-rank (== jnp.unique inverse) ------------------------------------
__global__ void k_hist_table(const u64* __restrict__ tab, u32* bcnt) {
  u32 i = blockIdx.x * 256 + threadIdx.x;
  u64 e = tab[i];
  if (e) atomicAdd(&bcnt[(u32)((e & KEYMASK) >> BSHIFT)], 1u);
}
__global__ void k_scatter_table(const u64* __restrict__ tab, const u32* __restrict__ boff,
                                u32* bfill, u64* bkeys) {
  u32 i = blockIdx.x * 256 + threadIdx.x;
  u64 e = tab[i];
  if (e) {
    u64 key = e & KEYMASK;
    u32 b = (u32)(key >> BSHIFT);
    u32 pos = boff[b] + atomicAdd(&bfill[b], 1u);
    bkeys[pos] = key;
  }
}
__global__ void k_rank(const u64* __restrict__ bkeys, const u32* __restrict__ bcnt,
                       const u32* __restrict__ boff, const u64* __restrict__ tab,
                       u32* rankArr, const u32* __restrict__ uniqueM) {
  u32 p = blockIdx.x * 256 + threadIdx.x;
  if (p >= *uniqueM) return;
  u64 key = bkeys[p];
  u32 b = (u32)(key >> BSHIFT);
  u32 st = boff[b], cn = bcnt[b];
  u32 r = st;
  for (u32 q = st; q < st + cn; ++q) r += (bkeys[q] < key) ? 1u : 0u;
  u64 want = key | BIT62;
  u32 s = hash_key(want);
  while (tab[s] != want) s = (s + 1) & CMASK;   // quiescent table: plain reads safe
  rankArr[s] = r;
}
__global__ void k_inv(const float* __restrict__ xyz, const int* __restrict__ comp,
                      const Comp* __restrict__ cc, const u64* __restrict__ tab,
                      const u32* __restrict__ rankArr, u32* inv, u32* counts) {
  int i = blockIdx.x * 256 + threadIdx.x;
  int c = comp[i];
  u64 key = make_key(xyz[3 * i], xyz[3 * i + 1], xyz[3 * i + 2], c,
                     cc[c].minx, cc[c].miny, cc[c].minz, cc[c].bestv);
  u64 want = key | BIT62;
  u32 s = hash_key(want);
  while (tab[s] != want) s = (s + 1) & CMASK;
  u32 r = rankArr[s];
  inv[i] = r;
  atomicAdd(&counts[r], 1u);
}

__global__ void k_pairs(const u32* __restrict__ inv, u64* pairA) {
  int i = blockIdx.x * 256 + threadIdx.x;
  pairA[i] = ((u64)inv[i] << 32) | (u32)i;
}

// ---- generic exclusive scan (3 kernels) -------------------------------------
__global__ void k_scan_part(const u32* __restrict__ in, u32* part, int n) {
  __shared__ u32 sh[256];
  int t = threadIdx.x;
  int base = blockIdx.x * 2048 + t * 8;
  u32 s = 0;
  for (int k = 0; k < 8; ++k) { int i = base + k; if (i < n) s += in[i]; }
  sh[t] = s; __syncthreads();
  for (int off = 1; off < 256; off <<= 1) {
    u32 a = (t >= off) ? sh[t - off] : 0u; __syncthreads();
    sh[t] += a; __syncthreads();
  }
  if (t == 255) part[blockIdx.x] = sh[255];
}
__global__ __launch_bounds__(1024) void k_scan_single(u32* a, int n) {
  __shared__ u32 sh[1024];
  int t = threadIdx.x;
  u32 v = (t < n) ? a[t] : 0u;
  sh[t] = v; __syncthreads();
  for (int off = 1; off < 1024; off <<= 1) {
    u32 x = (t >= off) ? sh[t - off] : 0u; __syncthreads();
    sh[t] += x; __syncthreads();
  }
  if (t < n) a[t] = sh[t] - v;
}
__global__ void k_scan_apply(const u32* __restrict__ in, const u32* __restrict__ part,
                             u32* out, int n) {
  __shared__ u32 sh[256];
  int t = threadIdx.x;
  int base = blockIdx.x * 2048 + t * 8;
  u32 vals[8]; u32 s = 0;
  for (int k = 0; k < 8; ++k) { int i = base + k; vals[k] = (i < n) ? in[i] : 0u; s += vals[k]; }
  sh[t] = s; __syncthreads();
  for (int off = 1; off < 256; off <<= 1) {
    u32 x = (t >= off) ? sh[t - off] : 0u; __syncthreads();
    sh[t] += x; __syncthreads();
  }
  u32 tb = sh[t] - s + part[blockIdx.x];
  u32 run = 0;
  for (int k = 0; k < 8; ++k) { int i = base + k; if (i < n) out[i] = tb + run; run += vals[k]; }
}

// ---- stable 7-bit LSD radix pass (sort pairs by inv; stability => idx order) -
__global__ __launch_bounds__(64) void k_radix_hist(const u64* __restrict__ src, u32* gh, int shift) {
  __shared__ u32 h[128 * 64];
  int t = threadIdx.x;
  for (int k = t; k < 128 * 64; k += 64) h[k] = 0u;
  __syncthreads();
  int base = blockIdx.x * 2048 + t * 32;
  for (int k = 0; k < 32; ++k) { u32 d = (u32)(src[base + k] >> shift) & 127u; h[d * 64 + t]++; }
  __syncthreads();
  for (int d = t; d < 128; d += 64) {
    u32 s = 0;
    for (int tt = 0; tt < 64; ++tt) s += h[d * 64 + tt];
    gh[d * 1024 + blockIdx.x] = s;
  }
}
__global__ __launch_bounds__(64) void k_radix_scatter(const u64* __restrict__ src, u64* dst,
                                                      const u32* __restrict__ ghs, int shift) {
  __shared__ u32 h[128 * 64]; __shared__ u32 sb[128];
  int t = threadIdx.x;
  for (int k = t; k < 128 * 64; k += 64) h[k] = 0u;
  __syncthreads();
  int base = blockIdx.x * 2048 + t * 32;
  for (int k = 0; k < 32; ++k) { u32 d = (u32)(src[base + k] >> shift) & 127u; h[d * 64 + t]++; }
  __syncthreads();
  for (int d = t; d < 128; d += 64) {
    u32 run = 0;
    for (int tt = 0; tt < 64; ++tt) { u32 tmp = h[d * 64 + tt]; h[d * 64 + tt] = run; run += tmp; }
    sb[d] = ghs[d * 1024 + blockIdx.x];
  }
  __syncthreads();
  for (int k = 0; k < 32; ++k) {
    u64 v = src[base + k];
    u32 d = (u32)(v >> shift) & 127u;
    u32 pos = sb[d] + h[d * 64 + t];
    h[d * 64 + t]++;
    dst[pos] = v;
  }
}

// ---- in-index-order f32 sums per voxel (bit-exact vs sequential scatter-add) -
__global__ void k_sum_small(const u32* __restrict__ counts, const u32* __restrict__ voxOff,
                            const u64* __restrict__ pairF, const float* __restrict__ xyz,
                            float* centx, float* centy, float* centz,
                            u32* bigList, u32* bigCnt) {
  int v = blockIdx.x * 256 + threadIdx.x;
  u32 c = counts[v];
  if (!c) return;
  if (c > BIGV) { bigList[atomicAdd(bigCnt, 1u)] = (u32)v; return; }
  u32 off = voxOff[v];
  float sx = 0.f, sy = 0.f, sz = 0.f;
  for (u32 q = 0; q < c; ++q) {
    u32 idx = (u32)(pairF[off + q] & 0xFFFFFFFFULL);
    sx += xyz[3 * idx];
    sy += xyz[3 * idx + 1];
    sz += xyz[3 * idx + 2];
  }
  float fc = (float)c;
  centx[v] = sx / fc; centy[v] = sy / fc; centz[v] = sz / fc;
}
// one wave per big voxel: cooperative gather into LDS (double-buffered), then
// an in-order serial fold from LDS (all lanes redundantly -> broadcast, free).
__global__ __launch_bounds__(64) void k_sum_big(const u32* __restrict__ bigCnt,
                                                const u32* __restrict__ bigList,
                                                const u32* __restrict__ counts,
                                                const u32* __restrict__ voxOff,
                                                const u64* __restrict__ pairF,
                                                const float* __restrict__ xyz,
                                                float* centx, float* centy, float* centz) {
  __shared__ float bx[2][64], by[2][64], bz[2][64];
  int t = threadIdx.x;
  u32 nb = *bigCnt;
  for (u32 b = blockIdx.x; b < nb; b += gridDim.x) {
    u32 v = bigList[b];
    u32 c = counts[v];
    u32 off = voxOff[v];
    u32 nchunk = (c + 63u) >> 6;
    if ((u32)t < c) {
      u32 idx = (u32)(pairF[off + t] & 0xFFFFFFFFULL);
      bx[0][t] = xyz[3 * idx]; by[0][t] = xyz[3 * idx + 1]; bz[0][t] = xyz[3 * idx + 2];
    }
    __syncthreads();
    float sx = 0.f, sy = 0.f, sz = 0.f;
    int cur = 0;
    for (u32 ch = 0; ch < nchunk; ++ch) {
      u32 basen = (ch + 1) << 6;
      if (ch + 1 < nchunk && basen + (u32)t < c) {
        u32 idx = (u32)(pairF[off + basen + t] & 0xFFFFFFFFULL);
        bx[cur ^ 1][t] = xyz[3 * idx]; by[cur ^ 1][t] = xyz[3 * idx + 1]; bz[cur ^ 1][t] = xyz[3 * idx + 2];
      }
      u32 base = ch << 6;
      u32 m = c - base; if (m > 64u) m = 64u;
      for (u32 q = 0; q < m; ++q) { sx += bx[cur][q]; sy += by[cur][q]; sz += bz[cur][q]; }
      __syncthreads();
      cur ^= 1;
    }
    if (t == 0) {
      float fc = (float)c;
      centx[v] = sx / fc; centy[v] = sy / fc; centz[v] = sz / fc;
    }
    __syncthreads();
  }
}

__global__ void k_d(const float* __restrict__ xyz, const u32* __restrict__ inv,
                    const float* __restrict__ centx, const float* __restrict__ centy,
                    const float* __restrict__ centz, float* dArr, u32* dminb) {
  int i = blockIdx.x * 256 + threadIdx.x;
  u32 v = inv[i];
  float dx = xyz[3 * i] - centx[v];
  float dy = xyz[3 * i + 1] - centy[v];
  float dz = xyz[3 * i + 2] - centz[v];
  // no-FMA sum of squares, left-assoc (matches XLA reduce order)
  float dd = __fadd_rn(__fadd_rn(__fmul_rn(dx, dx), __fmul_rn(dy, dy)), __fmul_rn(dz, dz));
  dArr[i] = dd;
  atomicMin(&dminb[v], __float_as_uint(dd));  // dd >= 0: uint order == float order
}
__global__ void k_amin(const float* __restrict__ dArr, const u32* __restrict__ inv,
                       const u32* __restrict__ dminb, u32* amin) {
  int i = blockIdx.x * 256 + threadIdx.x;
  u32 v = inv[i];
  if (dArr[i] <= __uint_as_float(dminb[v])) atomicMin(&amin[v], (u32)i);
}
__global__ void k_out(const u32* __restrict__ counts, const u32* __restrict__ amin,
                      const float* __restrict__ xyz, float* out) {
  int j = blockIdx.x * 256 + threadIdx.x;
  u32 c = counts[j];
  float ox = 0.f, oy = 0.f, oz = 0.f, og = -1.0f, ov = 0.0f;
  if (c) {
    u32 idx = amin[j];
    ox = xyz[3 * idx]; oy = xyz[3 * idx + 1]; oz = xyz[3 * idx + 2];
    og = (float)idx; ov = 1.0f;
  }
  out[3 * j] = ox; out[3 * j + 1] = oy; out[3 * j + 2] = oz;
  out[3 * NPTS + j] = og;
  out[4 * NPTS + j] = ov;
}

// ---- launch -----------------------------------------------------------------
extern "C" void kernel_launch(void* const* d_in, const int* in_sizes, int n_in,
                              void* d_out, int out_size, void* d_ws, size_t ws_size,
                              hipStream_t stream) {
  const float* xyz = (const float*)d_in[0];
  const int* comp = (const int*)d_in[1];
  const int* salloc = (const int*)d_in[2];
  float* out = (float*)d_out;
  char* ws = (char*)d_ws;

  const size_t SZN = (size_t)NPTS * 4;
  size_t oGH = 8192;                     // 512KB
  size_t oPART = oGH + 524288;           // 4KB
  size_t oINV = 1u << 20;
  size_t oCNT = oINV + SZN;
  size_t oVOX = oCNT + SZN;
  size_t oD = oVOX + SZN;
  size_t oDMIN = oD + SZN;
  size_t oAMIN = oDMIN + SZN;
  size_t oCENT = oAMIN + SZN;            // 3*SZN
  size_t oPA = oCENT + 3 * SZN;
  size_t oPB = oPA + (size_t)NPTS * 8;
  size_t NEED = oPB + (size_t)NPTS * 8;  // ~105MB (tab spans pairA+pairB)
  if (ws_size < NEED) return;

  Comp* cc = (Comp*)(ws);
  u32* uniqueM = (u32*)(ws + 6144);
  u32* bigCnt = (u32*)(ws + 6208);
  u32* gh = (u32*)(ws + oGH);
  u32* part = (u32*)(ws + oPART);
  u32* inv = (u32*)(ws + oINV);
  u32* counts = (u32*)(ws + oCNT);
  u32* voxOff = (u32*)(ws + oVOX);
  float* dArr = (float*)(ws + oD);
  u32* dminb = (u32*)(ws + oDMIN);
  u32* amin = (u32*)(ws + oAMIN);
  float* centx = (float*)(ws + oCENT);
  float* centy = (float*)(ws + oCENT + SZN);
  float* centz = (float*)(ws + oCENT + 2 * SZN);
  u64* pairA = (u64*)(ws + oPA);
  u64* pairB = (u64*)(ws + oPB);
  // unions (liveness-disjoint):
  u64* tab = (u64*)(ws + oPA);           // 32MB over pairA+pairB; dead before k_pairs
  u32* rankArr = (u32*)(ws + oCENT);     // 16MB over cent; dead before k_sum_*
  u64* bkeys = (u64*)(ws + oCNT);        // 16MB over counts+voxOff; dead before memset(counts)
  u32* bcnt = (u32*)(ws + oD);           // 4MB over dArr; dead after k_rank
  u32* boff = (u32*)(ws + oD + 4194304); // 4MB over dArr
  u32* bfill = (u32*)(ws + oDMIN);       // 4MB over dminb; dead before memset(dminb)
  u32* bigList = (u32*)(ws + oD);        // over dArr; live k_sum_small..k_sum_big < k_d

  // Phase A: bbox + per-comp setup
  k_init_comp<<<1, 64, 0, stream>>>(cc, uniqueM, bigCnt);
  k_bbox<<<1024, 256, 0, stream>>>(xyz, comp, cc, NPTS);
  k_setup<<<1, 64, 0, stream>>>(cc, salloc);

  // Phase B: 8-iteration bisection on distinct-voxel count (cleared hash set/pass)
  for (int it = 0; it < 8; ++it) {
    hipMemsetAsync(tab, 0, (size_t)CAP * 8, stream);
    k_bisect_insert<<<NPTS / 256, 256, 0, stream>>>(xyz, comp, cc, tab);
    k_update<<<1, 64, 0, stream>>>(cc);
  }

  // Phase C: final voxelization + sorted-unique ranks
  hipMemsetAsync(tab, 0, (size_t)CAP * 8, stream);
  k_final_insert<<<NPTS / 256, 256, 0, stream>>>(xyz, comp, cc, tab, uniqueM);
  hipMemsetAsync(bcnt, 0, (size_t)NBUCK * 4, stream);
  hipMemsetAsync(bfill, 0, (size_t)NBUCK * 4, stream);
  k_hist_table<<<CAP / 256, 256, 0, stream>>>(tab, bcnt);
  k_scan_part<<<512, 256, 0, stream>>>(bcnt, part, NBUCK);
  k_scan_single<<<1, 1024, 0, stream>>>(part, 512);
  k_scan_apply<<<512, 256, 0, stream>>>(bcnt, part, boff, NBUCK);
  k_scatter_table<<<CAP / 256, 256, 0, stream>>>(tab, boff, bfill, bkeys);
  k_rank<<<NPTS / 256, 256, 0, stream>>>(bkeys, bcnt, boff, tab, rankArr, uniqueM);

  // Phase D: inv + counts, offsets, stable sort by inv
  hipMemsetAsync(counts, 0, SZN, stream);          // kills bkeys (dead)
  k_inv<<<NPTS / 256, 256, 0, stream>>>(xyz, comp, cc, tab, rankArr, inv, counts);
  k_scan_part<<<1024, 256, 0, stream>>>(counts, part, NPTS);
  k_scan_single<<<1, 1024, 0, stream>>>(part, 1024);
  k_scan_apply<<<1024, 256, 0, stream>>>(counts, part, voxOff, NPTS);
  k_pairs<<<NPTS / 256, 256, 0, stream>>>(inv, pairA);  // kills tab (dead)
  {
    const int shifts[3] = {32, 39, 46};  // inv occupies bits 32..52
    u64* src = pairA; u64* dst = pairB;
    for (int p = 0; p < 3; ++p) {
      k_radix_hist<<<1024, 64, 0, stream>>>(src, gh, shifts[p]);
      k_scan_part<<<64, 256, 0, stream>>>(gh, part, 131072);
      k_scan_single<<<1, 1024, 0, stream>>>(part, 64);
      k_scan_apply<<<64, 256, 0, stream>>>(gh, part, gh, 131072);
      k_radix_scatter<<<1024, 64, 0, stream>>>(src, dst, gh, shifts[p]);
      u64* t2 = src; src = dst; dst = t2;
    }
    // sorted pairs now in pairB (src)
    k_sum_small<<<NPTS / 256, 256, 0, stream>>>(counts, voxOff, src, xyz,
                                                centx, centy, centz, bigList, bigCnt);
    k_sum_big<<<4096, 64, 0, stream>>>(bigCnt, bigList, counts, voxOff, src, xyz,
                                       centx, centy, centz);
  }

  // Phase E: distances, argmin, outputs
  hipMemsetAsync(dminb, 0xFF, SZN, stream);        // kills bfill (dead)
  hipMemsetAsync(amin, 0xFF, SZN, stream);
  k_d<<<NPTS / 256, 256, 0, stream>>>(xyz, inv, centx, centy, centz, dArr, dminb);
  k_amin<<<NPTS / 256, 256, 0, stream>>>(dArr, inv, dminb, amin);
  k_out<<<NPTS / 256, 256, 0, stream>>>(counts, amin, xyz, out);
}